// Round 1
// baseline (2755.308 us; speedup 1.0000x reference)
//
#include <hip/hip_runtime.h>
#include <stdint.h>

#define NB 128   // batch
#define NT 512   // time steps
#define NI 256   // input dim
#define NH 512   // hidden dim
#define NO 256   // output dim

// ---------- bf16 helpers (manual RNE, no header-type dependence) ----------
__device__ __forceinline__ uint16_t f2bf(float x) {
  uint32_t u = __float_as_uint(x);
  return (uint16_t)((u + 0x7fffu + ((u >> 16) & 1u)) >> 16);
}
__device__ __forceinline__ uint32_t pack2bf(float a, float b) {
  return (uint32_t)f2bf(a) | ((uint32_t)f2bf(b) << 16);
}

#if __has_builtin(__builtin_amdgcn_fdot2_f32_bf16)
typedef __bf16 bf16x2_t __attribute__((ext_vector_type(2)));
#define HAVE_DOT2 1
#endif

// acc += lo(w)*lo(h) + hi(w)*hi(h), bf16 pairs
__device__ __forceinline__ float dot2bf(uint32_t w, uint32_t h, float acc) {
#ifdef HAVE_DOT2
  return __builtin_amdgcn_fdot2_f32_bf16(__builtin_bit_cast(bf16x2_t, w),
                                         __builtin_bit_cast(bf16x2_t, h), acc, false);
#else
  float wl = __uint_as_float(w << 16), wh = __uint_as_float(w & 0xffff0000u);
  float hl = __uint_as_float(h << 16), hh = __uint_as_float(h & 0xffff0000u);
  return fmaf(wh, hh, fmaf(wl, hl, acc));
#endif
}

// ---------- kernel 0: pack W_hh^T as bf16 pairs; transpose W_out ----------
// WT2[k2*NH + j] = (bf16(W_hh[j][2k2]), bf16(W_hh[j][2k2+1]))   (256 x 512 words)
// WoT[k*NO + o]  = W_out[o][k]                                  (512 x 256 fp32)
__global__ __launch_bounds__(256) void prep_kernel(const float* __restrict__ Whh,
                                                   const float* __restrict__ Wout,
                                                   uint32_t* __restrict__ WT2,
                                                   float* __restrict__ WoT) {
  int idx = blockIdx.x * 256 + threadIdx.x;
  if (idx < NH * NH / 2) {
    int j = idx & (NH - 1);
    int k2 = idx >> 9;
    float a = Whh[(size_t)j * NH + 2 * k2];
    float b = Whh[(size_t)j * NH + 2 * k2 + 1];
    WT2[(size_t)k2 * NH + j] = pack2bf(a, b);
  } else {
    int i = idx - NH * NH / 2;
    int o = i & (NO - 1);
    int k = i >> 8;
    WoT[(size_t)k * NO + o] = Wout[(size_t)o * NH + k];
  }
}

// ---------- kernel 1: x_proj GEMM (fp32 compute, bf16 store) ----------
// XP[m][n] = sum_i A[m][i] * W_ih[n][i] + (b_ih[n]+b_hh[n]),  m in [0,65536), n in [0,512)
#define BM 128
#define BN 128
#define BK 16
__global__ __launch_bounds__(256) void xproj_kernel(const float* __restrict__ A,
                                                    const float* __restrict__ Wih,
                                                    const float* __restrict__ bih,
                                                    const float* __restrict__ bhh,
                                                    uint16_t* __restrict__ XP) {
  __shared__ float As[BK][BM + 4];
  __shared__ float Bs[BK][BN + 4];
  const int tid = threadIdx.x;
  const int m0 = blockIdx.x * BM;
  const int n0 = blockIdx.y * BN;
  const int lrow = tid >> 2;        // 0..63
  const int lk = (tid & 3) * 4;     // 0,4,8,12
  const int tx = tid & 15;          // n micro-tile
  const int ty = tid >> 4;          // m micro-tile
  float acc[8][8] = {};

  for (int k0 = 0; k0 < NI; k0 += BK) {
    float4 a0 = *(const float4*)&A[(size_t)(m0 + lrow) * NI + k0 + lk];
    float4 a1 = *(const float4*)&A[(size_t)(m0 + lrow + 64) * NI + k0 + lk];
    float4 b0 = *(const float4*)&Wih[(size_t)(n0 + lrow) * NI + k0 + lk];
    float4 b1 = *(const float4*)&Wih[(size_t)(n0 + lrow + 64) * NI + k0 + lk];
    __syncthreads();   // previous iteration's compute done before overwriting LDS
    As[lk + 0][lrow] = a0.x; As[lk + 1][lrow] = a0.y; As[lk + 2][lrow] = a0.z; As[lk + 3][lrow] = a0.w;
    As[lk + 0][lrow + 64] = a1.x; As[lk + 1][lrow + 64] = a1.y; As[lk + 2][lrow + 64] = a1.z; As[lk + 3][lrow + 64] = a1.w;
    Bs[lk + 0][lrow] = b0.x; Bs[lk + 1][lrow] = b0.y; Bs[lk + 2][lrow] = b0.z; Bs[lk + 3][lrow] = b0.w;
    Bs[lk + 0][lrow + 64] = b1.x; Bs[lk + 1][lrow + 64] = b1.y; Bs[lk + 2][lrow + 64] = b1.z; Bs[lk + 3][lrow + 64] = b1.w;
    __syncthreads();
#pragma unroll
    for (int kk = 0; kk < BK; ++kk) {
      float4 av0 = *(const float4*)&As[kk][ty * 8];
      float4 av1 = *(const float4*)&As[kk][ty * 8 + 4];
      float4 bv0 = *(const float4*)&Bs[kk][tx * 8];
      float4 bv1 = *(const float4*)&Bs[kk][tx * 8 + 4];
      float am[8] = {av0.x, av0.y, av0.z, av0.w, av1.x, av1.y, av1.z, av1.w};
      float bn_[8] = {bv0.x, bv0.y, bv0.z, bv0.w, bv1.x, bv1.y, bv1.z, bv1.w};
#pragma unroll
      for (int r = 0; r < 8; ++r)
#pragma unroll
        for (int c = 0; c < 8; ++c) acc[r][c] = fmaf(am[r], bn_[c], acc[r][c]);
    }
  }

  float bias[8];
#pragma unroll
  for (int c = 0; c < 8; ++c) bias[c] = bih[n0 + tx * 8 + c] + bhh[n0 + tx * 8 + c];
#pragma unroll
  for (int r = 0; r < 8; ++r) {
    int m = m0 + ty * 8 + r;
    uint4 w;
    w.x = pack2bf(acc[r][0] + bias[0], acc[r][1] + bias[1]);
    w.y = pack2bf(acc[r][2] + bias[2], acc[r][3] + bias[3]);
    w.z = pack2bf(acc[r][4] + bias[4], acc[r][5] + bias[5]);
    w.w = pack2bf(acc[r][6] + bias[6], acc[r][7] + bias[7]);
    *(uint4*)&XP[(size_t)m * NH + n0 + tx * 8] = w;
  }
}

// ---------- kernel 2: recurrence (1 WG per batch) + fused readout ----------
__global__ __launch_bounds__(512) void recur_kernel(const uint32_t* __restrict__ WT2,
                                                    const float* __restrict__ WoT,
                                                    const uint16_t* __restrict__ XP,
                                                    const float* __restrict__ h0,
                                                    const float* __restrict__ bout,
                                                    float* __restrict__ out) {
  __shared__ __align__(16) uint16_t hs2[NH];  // bf16 copy of h (matvec input)
  __shared__ float hsf[NH];                   // fp32 h for readout
  const int j = threadIdx.x;
  const int b = blockIdx.x;
  const float invT = 1.0f / (float)NT;

  float hj = h0[j];                 // fp32 h state lives in a register
  hs2[j] = f2bf(hj);
  __syncthreads();

  const uint16_t* xpb = XP + (size_t)b * NT * NH;
  const uint32_t* hw = (const uint32_t*)hs2;

  for (int t = 0; t < NT; ++t) {
    float xpj = __uint_as_float((uint32_t)xpb[(size_t)t * NH + j] << 16);
    float y0 = 0.f, y1 = 0.f, y2 = 0.f, y3 = 0.f;
#pragma unroll 2
    for (int k2 = 0; k2 < NH / 2; k2 += 16) {
      uint32_t w[16];
#pragma unroll
      for (int u = 0; u < 16; ++u) w[u] = WT2[(size_t)(k2 + u) * NH + j];
      uint4 hA = *(const uint4*)(hw + k2);
      uint4 hB = *(const uint4*)(hw + k2 + 4);
      uint4 hC = *(const uint4*)(hw + k2 + 8);
      uint4 hD = *(const uint4*)(hw + k2 + 12);
      y0 = dot2bf(w[0], hA.x, y0);  y1 = dot2bf(w[1], hA.y, y1);
      y2 = dot2bf(w[2], hA.z, y2);  y3 = dot2bf(w[3], hA.w, y3);
      y0 = dot2bf(w[4], hB.x, y0);  y1 = dot2bf(w[5], hB.y, y1);
      y2 = dot2bf(w[6], hB.z, y2);  y3 = dot2bf(w[7], hB.w, y3);
      y0 = dot2bf(w[8], hC.x, y0);  y1 = dot2bf(w[9], hC.y, y1);
      y2 = dot2bf(w[10], hC.z, y2); y3 = dot2bf(w[11], hC.w, y3);
      y0 = dot2bf(w[12], hD.x, y0); y1 = dot2bf(w[13], hD.y, y1);
      y2 = dot2bf(w[14], hD.z, y2); y3 = dot2bf(w[15], hD.w, y3);
    }
    float y = (y0 + y1) + (y2 + y3);
    float hnew = fmaf(tanhf(xpj + y), invT, hj);
    __syncthreads();              // all reads of hs2 for this step done
    hs2[j] = f2bf(hnew);
    hj = hnew;
    __syncthreads();              // new h visible before next step
  }

  hsf[j] = hj;
  __syncthreads();

  // readout: out[b][o] = sum_k h[k] * W_out[o][k] + b_out[o]  (fp32 exact)
  if (j < NO) {
    float a0 = 0.f, a1 = 0.f;
#pragma unroll 4
    for (int k = 0; k < NH; k += 2) {
      a0 = fmaf(WoT[(size_t)k * NO + j], hsf[k], a0);
      a1 = fmaf(WoT[(size_t)(k + 1) * NO + j], hsf[k + 1], a1);
    }
    out[(size_t)b * NO + j] = a0 + a1 + bout[j];
  }
}

// ---------- launch ----------
extern "C" void kernel_launch(void* const* d_in, const int* in_sizes, int n_in,
                              void* d_out, int out_size, void* d_ws, size_t ws_size,
                              hipStream_t stream) {
  const float* inputs = (const float*)d_in[0];  // [128,512,256]
  const float* Wih    = (const float*)d_in[1];  // [512,256]
  const float* bih    = (const float*)d_in[2];  // [512]
  const float* Whh    = (const float*)d_in[3];  // [512,512]
  const float* bhh    = (const float*)d_in[4];  // [512]
  const float* Wout   = (const float*)d_in[5];  // [256,512]
  const float* bout   = (const float*)d_in[6];  // [256]
  const float* h0     = (const float*)d_in[7];  // [512]
  float* out = (float*)d_out;                   // [128,256]

  char* ws = (char*)d_ws;
  uint32_t* WT2 = (uint32_t*)ws;                      // 512 KB: bf16-packed W_hh^T
  float*    WoT = (float*)(ws + (512u << 10));        // 512 KB: W_out^T fp32
  uint16_t* XP  = (uint16_t*)(ws + (1u << 20));       // 64 MB: x_proj bf16

  hipLaunchKernelGGL(prep_kernel, dim3(1024), dim3(256), 0, stream, Whh, Wout, WT2, WoT);
  hipLaunchKernelGGL(xproj_kernel, dim3(NB * NT / BM, NH / BN), dim3(256), 0, stream,
                     inputs, Wih, bih, bhh, XP);
  hipLaunchKernelGGL(recur_kernel, dim3(NB), dim3(512), 0, stream,
                     WT2, WoT, XP, h0, bout, out);
}

// Round 2
// 1773.018 us; speedup vs baseline: 1.5540x; 1.5540x over previous
//
#include <hip/hip_runtime.h>
#include <stdint.h>

#define NB 128   // batch
#define NT 512   // time steps
#define NI 256   // input dim
#define NH 512   // hidden dim
#define NO 256   // output dim

// ---------- bf16 helpers ----------
__device__ __forceinline__ uint16_t f2bf(float x) {
  uint32_t u = __float_as_uint(x);
  return (uint16_t)((u + 0x7fffu + ((u >> 16) & 1u)) >> 16);
}
__device__ __forceinline__ uint32_t pack2bf(float a, float b) {
  return (uint32_t)f2bf(a) | ((uint32_t)f2bf(b) << 16);
}

#if __has_builtin(__builtin_amdgcn_fdot2_f32_bf16)
typedef __bf16 bf16x2_t __attribute__((ext_vector_type(2)));
#define HAVE_DOT2 1
#endif

__device__ __forceinline__ float dot2bf(uint32_t w, uint32_t h, float acc) {
#ifdef HAVE_DOT2
  return __builtin_amdgcn_fdot2_f32_bf16(__builtin_bit_cast(bf16x2_t, w),
                                         __builtin_bit_cast(bf16x2_t, h), acc, false);
#else
  float wl = __uint_as_float(w << 16), wh = __uint_as_float(w & 0xffff0000u);
  float hl = __uint_as_float(h << 16), hh = __uint_as_float(h & 0xffff0000u);
  return fmaf(wh, hh, fmaf(wl, hl, acc));
#endif
}

// ---------- kernel 0: pack W_hh into register-tile order; transpose W_out ----------
// Recur thread t (0..1023) owns outputs j = (t&127)*4 + jj (jj<4) and k-quarter
// kq = t>>7 (k2 in [kq*32, kq*32+32)). Its weight quad q (0..31): jj=q>>3, u8=q&7,
// word v of quad covers k2 = kq*32 + u8*4 + v.
// Stored so thread t loads WT2R4[q*1024 + t] as uint4 (coalesced 16B/lane).
__global__ __launch_bounds__(256) void prep_kernel(const float* __restrict__ Whh,
                                                   const float* __restrict__ Wout,
                                                   uint4* __restrict__ WT2R4,
                                                   float* __restrict__ WoT) {
  int idx = blockIdx.x * 256 + threadIdx.x;
  if (idx < 32 * 1024) {
    int q = idx >> 10, t = idx & 1023;
    int jj = q >> 3, u8 = q & 7;
    int j = (t & 127) * 4 + jj;
    int k2b = (t >> 7) * 32 + u8 * 4;            // first k2 of the quad
    const float* row = Whh + (size_t)j * NH + 2 * k2b;  // 8 consecutive floats
    float4 f0 = *(const float4*)row;
    float4 f1 = *(const float4*)(row + 4);
    uint4 w;
    w.x = pack2bf(f0.x, f0.y);
    w.y = pack2bf(f0.z, f0.w);
    w.z = pack2bf(f1.x, f1.y);
    w.w = pack2bf(f1.z, f1.w);
    WT2R4[idx] = w;
  } else {
    int i = idx - 32 * 1024;                     // 0..131071
    int o = i & (NO - 1);
    int k = i >> 8;
    WoT[(size_t)k * NO + o] = Wout[(size_t)o * NH + k];
  }
}

// ---------- kernel 1: x_proj GEMM (fp32 compute, bf16 store) ----------
#define BM 128
#define BN 128
#define BK 16
__global__ __launch_bounds__(256) void xproj_kernel(const float* __restrict__ A,
                                                    const float* __restrict__ Wih,
                                                    const float* __restrict__ bih,
                                                    const float* __restrict__ bhh,
                                                    uint16_t* __restrict__ XP) {
  __shared__ float As[BK][BM + 4];
  __shared__ float Bs[BK][BN + 4];
  const int tid = threadIdx.x;
  const int m0 = blockIdx.x * BM;
  const int n0 = blockIdx.y * BN;
  const int lrow = tid >> 2;
  const int lk = (tid & 3) * 4;
  const int tx = tid & 15;
  const int ty = tid >> 4;
  float acc[8][8] = {};

  for (int k0 = 0; k0 < NI; k0 += BK) {
    float4 a0 = *(const float4*)&A[(size_t)(m0 + lrow) * NI + k0 + lk];
    float4 a1 = *(const float4*)&A[(size_t)(m0 + lrow + 64) * NI + k0 + lk];
    float4 b0 = *(const float4*)&Wih[(size_t)(n0 + lrow) * NI + k0 + lk];
    float4 b1 = *(const float4*)&Wih[(size_t)(n0 + lrow + 64) * NI + k0 + lk];
    __syncthreads();
    As[lk + 0][lrow] = a0.x; As[lk + 1][lrow] = a0.y; As[lk + 2][lrow] = a0.z; As[lk + 3][lrow] = a0.w;
    As[lk + 0][lrow + 64] = a1.x; As[lk + 1][lrow + 64] = a1.y; As[lk + 2][lrow + 64] = a1.z; As[lk + 3][lrow + 64] = a1.w;
    Bs[lk + 0][lrow] = b0.x; Bs[lk + 1][lrow] = b0.y; Bs[lk + 2][lrow] = b0.z; Bs[lk + 3][lrow] = b0.w;
    Bs[lk + 0][lrow + 64] = b1.x; Bs[lk + 1][lrow + 64] = b1.y; Bs[lk + 2][lrow + 64] = b1.z; Bs[lk + 3][lrow + 64] = b1.w;
    __syncthreads();
#pragma unroll
    for (int kk = 0; kk < BK; ++kk) {
      float4 av0 = *(const float4*)&As[kk][ty * 8];
      float4 av1 = *(const float4*)&As[kk][ty * 8 + 4];
      float4 bv0 = *(const float4*)&Bs[kk][tx * 8];
      float4 bv1 = *(const float4*)&Bs[kk][tx * 8 + 4];
      float am[8] = {av0.x, av0.y, av0.z, av0.w, av1.x, av1.y, av1.z, av1.w};
      float bn_[8] = {bv0.x, bv0.y, bv0.z, bv0.w, bv1.x, bv1.y, bv1.z, bv1.w};
#pragma unroll
      for (int r = 0; r < 8; ++r)
#pragma unroll
        for (int c = 0; c < 8; ++c) acc[r][c] = fmaf(am[r], bn_[c], acc[r][c]);
    }
  }

  float bias[8];
#pragma unroll
  for (int c = 0; c < 8; ++c) bias[c] = bih[n0 + tx * 8 + c] + bhh[n0 + tx * 8 + c];
#pragma unroll
  for (int r = 0; r < 8; ++r) {
    int m = m0 + ty * 8 + r;
    uint4 w;
    w.x = pack2bf(acc[r][0] + bias[0], acc[r][1] + bias[1]);
    w.y = pack2bf(acc[r][2] + bias[2], acc[r][3] + bias[3]);
    w.z = pack2bf(acc[r][4] + bias[4], acc[r][5] + bias[5]);
    w.w = pack2bf(acc[r][6] + bias[6], acc[r][7] + bias[7]);
    *(uint4*)&XP[(size_t)m * NH + n0 + tx * 8] = w;
  }
}

// ---------- kernel 2: recurrence, W_hh register-stationary ----------
// 1 WG (1024 thr, 16 waves) per batch. Thread t: kq = t>>7, jbase = (t&127)*4.
// Weights: 32 uint4 in VGPRs. h broadcast from LDS; 8-way k-reduction via LDS.
__global__ __launch_bounds__(1024) void recur_kernel(const uint4* __restrict__ WT2R4,
                                                     const float* __restrict__ WoT,
                                                     const uint16_t* __restrict__ XP,
                                                     const float* __restrict__ h0,
                                                     const float* __restrict__ bout,
                                                     float* __restrict__ out) {
  __shared__ __align__(16) uint16_t hs2[NH];   // bf16 h (matvec input), 1 KB
  __shared__ float P[8 * NH];                  // k-split partials, 16 KB
  __shared__ float hsf[NH];                    // fp32 h for readout, 2 KB
  const int t = threadIdx.x;
  const int b = blockIdx.x;
  const int kq = t >> 7;
  const int jbase = (t & 127) * 4;
  const float invT = 1.0f / (float)NT;

  // ---- load this thread's weight tile into registers (coalesced) ----
  uint4 W[32];
#pragma unroll
  for (int q = 0; q < 32; ++q) W[q] = WT2R4[q * 1024 + t];

  // ---- init h ----
  float hj = 0.f;
  if (t < NH) {
    hj = h0[t];
    hs2[t] = f2bf(hj);
  }
  __syncthreads();

  const uint16_t* xpb = XP + (size_t)b * NT * NH;
  const uint32_t* hw = (const uint32_t*)hs2;

  for (int ts = 0; ts < NT; ++ts) {
    // issue XP load early; dot loop below hides its latency
    float xpj = 0.f;
    if (t < NH) xpj = __uint_as_float((uint32_t)xpb[(size_t)ts * NH + t] << 16);

    float a0 = 0.f, a1 = 0.f, a2 = 0.f, a3 = 0.f;
#pragma unroll
    for (int u8 = 0; u8 < 8; ++u8) {
      uint4 hv = *(const uint4*)(hw + kq * 32 + u8 * 4);  // wave-uniform broadcast
      a0 = dot2bf(W[u8].x, hv.x, a0);
      a0 = dot2bf(W[u8].y, hv.y, a0);
      a0 = dot2bf(W[u8].z, hv.z, a0);
      a0 = dot2bf(W[u8].w, hv.w, a0);
      a1 = dot2bf(W[8 + u8].x, hv.x, a1);
      a1 = dot2bf(W[8 + u8].y, hv.y, a1);
      a1 = dot2bf(W[8 + u8].z, hv.z, a1);
      a1 = dot2bf(W[8 + u8].w, hv.w, a1);
      a2 = dot2bf(W[16 + u8].x, hv.x, a2);
      a2 = dot2bf(W[16 + u8].y, hv.y, a2);
      a2 = dot2bf(W[16 + u8].z, hv.z, a2);
      a2 = dot2bf(W[16 + u8].w, hv.w, a2);
      a3 = dot2bf(W[24 + u8].x, hv.x, a3);
      a3 = dot2bf(W[24 + u8].y, hv.y, a3);
      a3 = dot2bf(W[24 + u8].z, hv.z, a3);
      a3 = dot2bf(W[24 + u8].w, hv.w, a3);
    }
    *(float4*)&P[kq * NH + jbase] = make_float4(a0, a1, a2, a3);
    __syncthreads();   // P visible; all hs2 reads of this step done

    if (t < NH) {
      float y = ((P[t] + P[NH + t]) + (P[2 * NH + t] + P[3 * NH + t])) +
                ((P[4 * NH + t] + P[5 * NH + t]) + (P[6 * NH + t] + P[7 * NH + t]));
      float hnew = fmaf(tanhf(xpj + y), invT, hj);
      hj = hnew;
      hs2[t] = f2bf(hnew);
    }
    __syncthreads();   // new h visible
  }

  if (t < NH) hsf[t] = hj;
  __syncthreads();

  // readout: out[b][o] = sum_k h[k] * W_out[o][k] + b_out[o] (fp32)
  if (t < NO) {
    float c0 = 0.f, c1 = 0.f;
#pragma unroll 4
    for (int k = 0; k < NH; k += 2) {
      c0 = fmaf(WoT[(size_t)k * NO + t], hsf[k], c0);
      c1 = fmaf(WoT[(size_t)(k + 1) * NO + t], hsf[k + 1], c1);
    }
    out[(size_t)b * NO + t] = c0 + c1 + bout[t];
  }
}

// ---------- launch ----------
extern "C" void kernel_launch(void* const* d_in, const int* in_sizes, int n_in,
                              void* d_out, int out_size, void* d_ws, size_t ws_size,
                              hipStream_t stream) {
  const float* inputs = (const float*)d_in[0];
  const float* Wih    = (const float*)d_in[1];
  const float* bih    = (const float*)d_in[2];
  const float* Whh    = (const float*)d_in[3];
  const float* bhh    = (const float*)d_in[4];
  const float* Wout   = (const float*)d_in[5];
  const float* bout   = (const float*)d_in[6];
  const float* h0     = (const float*)d_in[7];
  float* out = (float*)d_out;

  char* ws = (char*)d_ws;
  uint4*    WT2R4 = (uint4*)ws;                   // 512 KB
  float*    WoT   = (float*)(ws + (512u << 10));  // 512 KB
  uint16_t* XP    = (uint16_t*)(ws + (1u << 20)); // 64 MB

  hipLaunchKernelGGL(prep_kernel, dim3(640), dim3(256), 0, stream, Whh, Wout, WT2R4, WoT);
  hipLaunchKernelGGL(xproj_kernel, dim3(NB * NT / BM, NH / BN), dim3(256), 0, stream,
                     inputs, Wih, bih, bhh, XP);
  hipLaunchKernelGGL(recur_kernel, dim3(NB), dim3(1024), 0, stream,
                     WT2R4, WoT, XP, h0, bout, out);
}

// Round 3
// 1005.933 us; speedup vs baseline: 2.7391x; 1.7626x over previous
//
#include <hip/hip_runtime.h>
#include <stdint.h>

#define NB 128   // batch
#define NT 512   // time steps
#define NI 256   // input dim
#define NH 512   // hidden dim
#define NO 256   // output dim

// ---------- bf16 helpers ----------
__device__ __forceinline__ uint16_t f2bf(float x) {
  uint32_t u = __float_as_uint(x);
  return (uint16_t)((u + 0x7fffu + ((u >> 16) & 1u)) >> 16);
}
__device__ __forceinline__ uint32_t pack2bf(float a, float b) {
  return (uint32_t)f2bf(a) | ((uint32_t)f2bf(b) << 16);
}

#if __has_builtin(__builtin_amdgcn_fdot2_f32_bf16)
typedef __bf16 bf16x2_t __attribute__((ext_vector_type(2)));
#define HAVE_DOT2 1
#endif

__device__ __forceinline__ float dot2bf(uint32_t w, uint32_t h, float acc) {
#ifdef HAVE_DOT2
  return __builtin_amdgcn_fdot2_f32_bf16(__builtin_bit_cast(bf16x2_t, w),
                                         __builtin_bit_cast(bf16x2_t, h), acc, false);
#else
  float wl = __uint_as_float(w << 16), wh = __uint_as_float(w & 0xffff0000u);
  float hl = __uint_as_float(h << 16), hh = __uint_as_float(h & 0xffff0000u);
  return fmaf(wh, hh, fmaf(wl, hl, acc));
#endif
}

__device__ __forceinline__ float dot4x(uint4 w, uint4 h, float a) {
  a = dot2bf(w.x, h.x, a);
  a = dot2bf(w.y, h.y, a);
  a = dot2bf(w.z, h.z, a);
  a = dot2bf(w.w, h.w, a);
  return a;
}

// ---------- kernel 0: pack W_hh quads; transpose W_out ----------
// Recur thread t (0..511): owns j = (t&127)*4 + jj (jj<4), k-quarter kq = t>>7
// (k2 in [kq*64, kq*64+64), i.e. k in [kq*128, kq*128+128)).
// Quad q = jj*16 + c (c = chunk 0..15): uint4 = bf16-pairs of
// W_hh[j][2*k2b .. 2*k2b+7], k2b = kq*64 + c*4.
// Stored at WQ[q*512 + t] so loads are lane-contiguous uint4.
__global__ __launch_bounds__(256) void prep_kernel(const float* __restrict__ Whh,
                                                   const float* __restrict__ Wout,
                                                   uint4* __restrict__ WQ,
                                                   float* __restrict__ WoT) {
  int idx = blockIdx.x * 256 + threadIdx.x;
  if (idx < 64 * 512) {
    int q = idx >> 9, t = idx & 511;
    int jj = q >> 4, c = q & 15;
    int j = (t & 127) * 4 + jj;
    int k2b = (t >> 7) * 64 + c * 4;
    const float* row = Whh + (size_t)j * NH + 2 * k2b;  // 8 consecutive floats
    float4 f0 = *(const float4*)row;
    float4 f1 = *(const float4*)(row + 4);
    uint4 w;
    w.x = pack2bf(f0.x, f0.y);
    w.y = pack2bf(f0.z, f0.w);
    w.z = pack2bf(f1.x, f1.y);
    w.w = pack2bf(f1.z, f1.w);
    WQ[idx] = w;
  } else {
    int i = idx - 64 * 512;                 // 0..131071
    int o = i & (NO - 1);
    int k = i >> 8;
    WoT[(size_t)k * NO + o] = Wout[(size_t)o * NH + k];
  }
}

// ---------- kernel 1: x_proj GEMM (fp32 compute, bf16 store) ----------
#define BM 128
#define BN 128
#define BK 16
__global__ __launch_bounds__(256) void xproj_kernel(const float* __restrict__ A,
                                                    const float* __restrict__ Wih,
                                                    const float* __restrict__ bih,
                                                    const float* __restrict__ bhh,
                                                    uint16_t* __restrict__ XP) {
  __shared__ float As[BK][BM + 4];
  __shared__ float Bs[BK][BN + 4];
  const int tid = threadIdx.x;
  const int m0 = blockIdx.x * BM;
  const int n0 = blockIdx.y * BN;
  const int lrow = tid >> 2;
  const int lk = (tid & 3) * 4;
  const int tx = tid & 15;
  const int ty = tid >> 4;
  float acc[8][8] = {};

  for (int k0 = 0; k0 < NI; k0 += BK) {
    float4 a0 = *(const float4*)&A[(size_t)(m0 + lrow) * NI + k0 + lk];
    float4 a1 = *(const float4*)&A[(size_t)(m0 + lrow + 64) * NI + k0 + lk];
    float4 b0 = *(const float4*)&Wih[(size_t)(n0 + lrow) * NI + k0 + lk];
    float4 b1 = *(const float4*)&Wih[(size_t)(n0 + lrow + 64) * NI + k0 + lk];
    __syncthreads();
    As[lk + 0][lrow] = a0.x; As[lk + 1][lrow] = a0.y; As[lk + 2][lrow] = a0.z; As[lk + 3][lrow] = a0.w;
    As[lk + 0][lrow + 64] = a1.x; As[lk + 1][lrow + 64] = a1.y; As[lk + 2][lrow + 64] = a1.z; As[lk + 3][lrow + 64] = a1.w;
    Bs[lk + 0][lrow] = b0.x; Bs[lk + 1][lrow] = b0.y; Bs[lk + 2][lrow] = b0.z; Bs[lk + 3][lrow] = b0.w;
    Bs[lk + 0][lrow + 64] = b1.x; Bs[lk + 1][lrow + 64] = b1.y; Bs[lk + 2][lrow + 64] = b1.z; Bs[lk + 3][lrow + 64] = b1.w;
    __syncthreads();
#pragma unroll
    for (int kk = 0; kk < BK; ++kk) {
      float4 av0 = *(const float4*)&As[kk][ty * 8];
      float4 av1 = *(const float4*)&As[kk][ty * 8 + 4];
      float4 bv0 = *(const float4*)&Bs[kk][tx * 8];
      float4 bv1 = *(const float4*)&Bs[kk][tx * 8 + 4];
      float am[8] = {av0.x, av0.y, av0.z, av0.w, av1.x, av1.y, av1.z, av1.w};
      float bn_[8] = {bv0.x, bv0.y, bv0.z, bv0.w, bv1.x, bv1.y, bv1.z, bv1.w};
#pragma unroll
      for (int r = 0; r < 8; ++r)
#pragma unroll
        for (int c = 0; c < 8; ++c) acc[r][c] = fmaf(am[r], bn_[c], acc[r][c]);
    }
  }

  float bias[8];
#pragma unroll
  for (int c = 0; c < 8; ++c) bias[c] = bih[n0 + tx * 8 + c] + bhh[n0 + tx * 8 + c];
#pragma unroll
  for (int r = 0; r < 8; ++r) {
    int m = m0 + ty * 8 + r;
    uint4 w;
    w.x = pack2bf(acc[r][0] + bias[0], acc[r][1] + bias[1]);
    w.y = pack2bf(acc[r][2] + bias[2], acc[r][3] + bias[3]);
    w.z = pack2bf(acc[r][4] + bias[4], acc[r][5] + bias[5]);
    w.w = pack2bf(acc[r][6] + bias[6], acc[r][7] + bias[7]);
    *(uint4*)&XP[(size_t)m * NH + n0 + tx * 8] = w;
  }
}

// ---------- kernel 2: recurrence, W_hh split registers (208 words) + LDS (48 words) ----------
// 512 threads (8 waves, 2/SIMD, 256-VGPR budget). Thread t: 4 outputs
// j = (t&127)*4+jj over k-quarter kq=t>>7. jj=0..2 chunks 0..15 and jj=3
// chunks 0..3 in VGPRs (52 uint4); jj=3 chunks 4..15 in LDS (96 KB).
__global__ __launch_bounds__(512, 2) void recur_kernel(const uint4* __restrict__ WQ,
                                                       const float* __restrict__ WoT,
                                                       const uint16_t* __restrict__ XP,
                                                       const float* __restrict__ h0,
                                                       const float* __restrict__ bout,
                                                       float* __restrict__ out) {
  __shared__ uint4 WL[12][512];                 // 96 KB: jj=3, chunks 4..15
  __shared__ __align__(16) uint16_t h2[2][NH];  // 2 KB: bf16 h, double-buffered
  __shared__ float P[4][NH];                    // 8 KB: k-split partials
  __shared__ float hsf[NH];                     // 2 KB: fp32 h for readout
  const int t = threadIdx.x;
  const int b = blockIdx.x;
  const int kq = t >> 7;
  const int jb = (t & 127) * 4;
  const float invT = 1.0f / (float)NT;

  // ---- weights: 52 quads to registers (coalesced), 12 quads to LDS ----
  uint4 Wr[52];
#pragma unroll
  for (int q = 0; q < 52; ++q) Wr[q] = WQ[q * 512 + t];
#pragma unroll
  for (int c = 0; c < 12; ++c) WL[c][t] = WQ[(52 + c) * 512 + t];

  // ---- init h ----
  float hj = h0[t];
  h2[0][t] = f2bf(hj);
  __syncthreads();

  const uint16_t* xpb = XP + (size_t)b * NT * NH;

  for (int ts = 0; ts < NT; ++ts) {
    const int cur = ts & 1;
    // issue XP load early; dot loop hides its latency
    float xpj = __uint_as_float((uint32_t)xpb[(size_t)ts * NH + t] << 16);

    const uint32_t* hw = (const uint32_t*)h2[cur];
    float a0 = 0.f, a1 = 0.f, a2 = 0.f, a3 = 0.f;
#pragma unroll
    for (int c = 0; c < 16; ++c) {
      uint4 hv = *(const uint4*)(hw + kq * 64 + c * 4);  // wave-uniform broadcast
      a0 = dot4x(Wr[c], hv, a0);
      a1 = dot4x(Wr[16 + c], hv, a1);
      a2 = dot4x(Wr[32 + c], hv, a2);
      uint4 w3 = (c < 4) ? Wr[48 + c] : WL[c - 4][t];
      a3 = dot4x(w3, hv, a3);
    }
    *(float4*)&P[kq][jb] = make_float4(a0, a1, a2, a3);
    __syncthreads();   // P visible; all h2[cur] reads done

    float y = (P[0][t] + P[1][t]) + (P[2][t] + P[3][t]);
    float hnew = fmaf(tanhf(xpj + y), invT, hj);
    hj = hnew;
    h2[cur ^ 1][t] = f2bf(hnew);
    __syncthreads();   // new h visible
  }

  hsf[t] = hj;
  __syncthreads();

  // readout: out[b][o] = sum_k h[k] * W_out[o][k] + b_out[o] (fp32)
  if (t < NO) {
    float c0 = 0.f, c1 = 0.f;
#pragma unroll 4
    for (int k = 0; k < NH; k += 2) {
      c0 = fmaf(WoT[(size_t)k * NO + t], hsf[k], c0);
      c1 = fmaf(WoT[(size_t)(k + 1) * NO + t], hsf[k + 1], c1);
    }
    out[(size_t)b * NO + t] = c0 + c1 + bout[t];
  }
}

// ---------- launch ----------
extern "C" void kernel_launch(void* const* d_in, const int* in_sizes, int n_in,
                              void* d_out, int out_size, void* d_ws, size_t ws_size,
                              hipStream_t stream) {
  const float* inputs = (const float*)d_in[0];
  const float* Wih    = (const float*)d_in[1];
  const float* bih    = (const float*)d_in[2];
  const float* Whh    = (const float*)d_in[3];
  const float* bhh    = (const float*)d_in[4];
  const float* Wout   = (const float*)d_in[5];
  const float* bout   = (const float*)d_in[6];
  const float* h0     = (const float*)d_in[7];
  float* out = (float*)d_out;

  char* ws = (char*)d_ws;
  uint4*    WQ  = (uint4*)ws;                    // 512 KB: packed W_hh quads
  float*    WoT = (float*)(ws + (512u << 10));   // 512 KB: W_out^T fp32
  uint16_t* XP  = (uint16_t*)(ws + (1u << 20));  // 64 MB: x_proj bf16

  hipLaunchKernelGGL(prep_kernel, dim3(640), dim3(256), 0, stream, Whh, Wout, WQ, WoT);
  hipLaunchKernelGGL(xproj_kernel, dim3(NB * NT / BM, NH / BN), dim3(256), 0, stream,
                     inputs, Wih, bih, bhh, XP);
  hipLaunchKernelGGL(recur_kernel, dim3(NB), dim3(512), 0, stream,
                     WQ, WoT, XP, h0, bout, out);
}

// Round 4
// 998.854 us; speedup vs baseline: 2.7585x; 1.0071x over previous
//
#include <hip/hip_runtime.h>
#include <stdint.h>

#define NB 128   // batch
#define NT 512   // time steps
#define NI 256   // input dim
#define NH 512   // hidden dim
#define NO 256   // output dim

// ---------- bf16 helpers ----------
__device__ __forceinline__ uint16_t f2bf(float x) {
  uint32_t u = __float_as_uint(x);
  return (uint16_t)((u + 0x7fffu + ((u >> 16) & 1u)) >> 16);
}
__device__ __forceinline__ uint32_t pack2bf(float a, float b) {
  return (uint32_t)f2bf(a) | ((uint32_t)f2bf(b) << 16);
}

#if __has_builtin(__builtin_amdgcn_fdot2_f32_bf16)
typedef __bf16 bf16x2_t __attribute__((ext_vector_type(2)));
#define HAVE_DOT2 1
#endif

__device__ __forceinline__ float dot2bf(uint32_t w, uint32_t h, float acc) {
#ifdef HAVE_DOT2
  return __builtin_amdgcn_fdot2_f32_bf16(__builtin_bit_cast(bf16x2_t, w),
                                         __builtin_bit_cast(bf16x2_t, h), acc, false);
#else
  float wl = __uint_as_float(w << 16), wh = __uint_as_float(w & 0xffff0000u);
  float hl = __uint_as_float(h << 16), hh = __uint_as_float(h & 0xffff0000u);
  return fmaf(wh, hh, fmaf(wl, hl, acc));
#endif
}

__device__ __forceinline__ float dot4x(uint4 w, uint4 h, float a) {
  a = dot2bf(w.x, h.x, a);
  a = dot2bf(w.y, h.y, a);
  a = dot2bf(w.z, h.z, a);
  a = dot2bf(w.w, h.w, a);
  return a;
}

__device__ __forceinline__ float fast_tanh(float x) {
  // tanh(x) = 1 - 2/(e^{2x}+1); correct limits at +/-inf, no branches
  float e = __expf(2.0f * x);
#if __has_builtin(__builtin_amdgcn_rcpf)
  return 1.0f - 2.0f * __builtin_amdgcn_rcpf(e + 1.0f);
#else
  return 1.0f - 2.0f / (e + 1.0f);
#endif
}

typedef __bf16 bf16x8 __attribute__((ext_vector_type(8)));
typedef float f32x4 __attribute__((ext_vector_type(4)));

// ---------- kernel 0: pack W_hh quads; Wih->bf16; transpose W_out; bias sum ----------
// Recur thread t (0..511): kq8 = t>>6 (k2 in [kq8*32,+32)), owns j = (t&63)*8 + jj (jj<8).
// Quad q = jj*8 + c (c=0..7): uint4 = bf16-pairs of W_hh[j][2*k2b..+8], k2b = kq8*32 + c*4.
// Stored at WQ[q*512 + t]. q<52 -> registers, q>=52 -> LDS in recur.
__global__ __launch_bounds__(256) void prep_kernel(const float* __restrict__ Whh,
                                                   const float* __restrict__ Wih,
                                                   const float* __restrict__ Wout,
                                                   const float* __restrict__ bih,
                                                   const float* __restrict__ bhh,
                                                   uint4* __restrict__ WQ,
                                                   float* __restrict__ WoT,
                                                   uint2* __restrict__ Wihb32,
                                                   float* __restrict__ BS) {
  int idx = blockIdx.x * 256 + threadIdx.x;
  if (idx < 32768) {                       // WQ quads
    int q = idx >> 9, t = idx & 511;
    int jj = q >> 3, c = q & 7;
    int j = (t & 63) * 8 + jj;
    int k2b = (t >> 6) * 32 + c * 4;
    const float* row = Whh + (size_t)j * NH + 2 * k2b;
    float4 f0 = *(const float4*)row;
    float4 f1 = *(const float4*)(row + 4);
    uint4 w;
    w.x = pack2bf(f0.x, f0.y);
    w.y = pack2bf(f0.z, f0.w);
    w.z = pack2bf(f1.x, f1.y);
    w.w = pack2bf(f1.z, f1.w);
    WQ[idx] = w;
  } else if (idx < 65536) {                // Wih -> bf16 (same row-major layout)
    int i = idx - 32768;
    float4 f = *(const float4*)(Wih + (size_t)i * 4);
    uint2 p;
    p.x = pack2bf(f.x, f.y);
    p.y = pack2bf(f.z, f.w);
    Wihb32[i] = p;
  } else if (idx < 98304) {                // W_out transpose (fp32)
    int i = idx - 65536;
    int o4 = (i & 63) * 4;
    int k = i >> 6;
    float4 v;
    v.x = Wout[(size_t)(o4 + 0) * NH + k];
    v.y = Wout[(size_t)(o4 + 1) * NH + k];
    v.z = Wout[(size_t)(o4 + 2) * NH + k];
    v.w = Wout[(size_t)(o4 + 3) * NH + k];
    *(float4*)&WoT[(size_t)k * NO + o4] = v;
  } else if (idx < 98816) {                // bias sum
    int n = idx - 98304;
    BS[n] = bih[n] + bhh[n];
  }
}

// ---------- kernel 1: x_proj GEMM via bf16 MFMA ----------
// XP[m][n] = sum_k inputs[m][k]*Wih[n][k] + BS[n].
// Tile as D[n][m]: arg0 = Wih frag (rows -> D rows = n), arg1 = inputs frag
// (rows -> D cols = m). D lane map: col=lane&15, row=quad*4+r  =>  lane holds
// 4 consecutive n at fixed m -> pack to one dwordx2 store per tile.
// WG = 256 thr (4 waves); wave w covers m in [m0+16w,+16), all 512 n (32 tiles).
__global__ __launch_bounds__(256, 2) void xproj_kernel(const float* __restrict__ A,
                                                       const uint16_t* __restrict__ Wihb,
                                                       const float* __restrict__ BS,
                                                       uint16_t* __restrict__ XP) {
  const int w = threadIdx.x >> 6;
  const int l = threadIdx.x & 63;
  const int sl = l & 15, quad = l >> 4;
  const int m = blockIdx.x * 64 + w * 16 + sl;   // input row this lane supplies

  f32x4 acc[32] = {};
  const float* arow = A + (size_t)m * NI;

  for (int k0 = 0; k0 < NI; k0 += 32) {
    float4 f0 = *(const float4*)(arow + k0 + quad * 8);
    float4 f1 = *(const float4*)(arow + k0 + quad * 8 + 4);
    uint4 ap;
    ap.x = pack2bf(f0.x, f0.y);
    ap.y = pack2bf(f0.z, f0.w);
    ap.z = pack2bf(f1.x, f1.y);
    ap.w = pack2bf(f1.z, f1.w);
    bf16x8 afrag = __builtin_bit_cast(bf16x8, ap);
#pragma unroll
    for (int u = 0; u < 32; ++u) {
      uint4 bp = *(const uint4*)(Wihb + (size_t)(u * 16 + sl) * NI + k0 + quad * 8);
      acc[u] = __builtin_amdgcn_mfma_f32_16x16x32_bf16(
          __builtin_bit_cast(bf16x8, bp), afrag, acc[u], 0, 0, 0);
    }
  }

  uint16_t* xrow = XP + (size_t)m * NH;
#pragma unroll
  for (int u = 0; u < 32; ++u) {
    float4 bs = *(const float4*)(BS + u * 16 + quad * 4);
    uint2 pw;
    pw.x = pack2bf(acc[u][0] + bs.x, acc[u][1] + bs.y);
    pw.y = pack2bf(acc[u][2] + bs.z, acc[u][3] + bs.w);
    *(uint2*)(xrow + u * 16 + quad * 4) = pw;
  }
}

// ---------- kernel 2: recurrence, jper=8 / S=8, W_hh reg(208w)+LDS(48w) ----------
__global__ __launch_bounds__(512, 2) void recur_kernel(const uint4* __restrict__ WQ,
                                                       const float* __restrict__ WoT,
                                                       const uint16_t* __restrict__ XP,
                                                       const float* __restrict__ h0,
                                                       const float* __restrict__ bout,
                                                       float* __restrict__ out) {
  __shared__ uint4 WL[12][512];                 // 96 KB: quads q=52..63
  __shared__ __align__(16) uint16_t h2[2][NH];  // 2 KB
  __shared__ float P[8][NH];                    // 16 KB: k-split partials
  __shared__ float hsf[NH];                     // 2 KB
  const int t = threadIdx.x;
  const int b = blockIdx.x;
  const int kq8 = t >> 6;          // k-eighth
  const int jb = (t & 63) * 8;     // first owned output
  const float invT = 1.0f / (float)NT;

  uint4 Wr[52];
#pragma unroll
  for (int q = 0; q < 52; ++q) Wr[q] = WQ[q * 512 + t];
#pragma unroll
  for (int i = 0; i < 12; ++i) WL[i][t] = WQ[(52 + i) * 512 + t];

  float hj = h0[t];
  h2[0][t] = f2bf(hj);
  __syncthreads();

  const uint16_t* xpb = XP + (size_t)b * NT * NH;

  for (int ts = 0; ts < NT; ++ts) {
    const int cur = ts & 1;
    float xpj = __uint_as_float((uint32_t)xpb[(size_t)ts * NH + t] << 16);

    const uint32_t* hw = (const uint32_t*)h2[cur] + kq8 * 32;
    float a0 = 0.f, a1 = 0.f, a2 = 0.f, a3 = 0.f;
    float a4 = 0.f, a5 = 0.f, a6 = 0.f, a7 = 0.f;

    // 2-deep h prefetch, 1-deep LDS-weight prefetch
    uint4 hv0 = *(const uint4*)(hw);
    uint4 hv1 = *(const uint4*)(hw + 4);
    uint4 w6n = Wr[48];          // (jj=6, c=0)
    uint4 w7n = WL[4][t];        // (jj=7, c=0)
#pragma unroll
    for (int c = 0; c < 8; ++c) {
      uint4 hv = hv0;
      hv0 = hv1;
      if (c < 6) hv1 = *(const uint4*)(hw + (c + 2) * 4);
      uint4 w6 = w6n, w7 = w7n;
      if (c < 7) {
        w6n = (c + 1 < 4) ? Wr[48 + c + 1] : WL[c - 3][t];
        w7n = WL[5 + c][t];
      }
      a0 = dot4x(Wr[c], hv, a0);
      a1 = dot4x(Wr[8 + c], hv, a1);
      a2 = dot4x(Wr[16 + c], hv, a2);
      a3 = dot4x(Wr[24 + c], hv, a3);
      a4 = dot4x(Wr[32 + c], hv, a4);
      a5 = dot4x(Wr[40 + c], hv, a5);
      a6 = dot4x(w6, hv, a6);
      a7 = dot4x(w7, hv, a7);
    }
    *(float4*)&P[kq8][jb] = make_float4(a0, a1, a2, a3);
    *(float4*)&P[kq8][jb + 4] = make_float4(a4, a5, a6, a7);
    __syncthreads();   // P visible; all h2[cur] reads done

    float y = ((P[0][t] + P[1][t]) + (P[2][t] + P[3][t])) +
              ((P[4][t] + P[5][t]) + (P[6][t] + P[7][t]));
    float hnew = fmaf(fast_tanh(xpj + y), invT, hj);
    hj = hnew;
    h2[cur ^ 1][t] = f2bf(hnew);
    __syncthreads();   // new h visible
  }

  hsf[t] = hj;
  __syncthreads();

  if (t < NO) {
    float c0 = 0.f, c1 = 0.f;
#pragma unroll 4
    for (int k = 0; k < NH; k += 2) {
      c0 = fmaf(WoT[(size_t)k * NO + t], hsf[k], c0);
      c1 = fmaf(WoT[(size_t)(k + 1) * NO + t], hsf[k + 1], c1);
    }
    out[(size_t)b * NO + t] = c0 + c1 + bout[t];
  }
}

// ---------- launch ----------
extern "C" void kernel_launch(void* const* d_in, const int* in_sizes, int n_in,
                              void* d_out, int out_size, void* d_ws, size_t ws_size,
                              hipStream_t stream) {
  const float* inputs = (const float*)d_in[0];
  const float* Wih    = (const float*)d_in[1];
  const float* bih    = (const float*)d_in[2];
  const float* Whh    = (const float*)d_in[3];
  const float* bhh    = (const float*)d_in[4];
  const float* Wout   = (const float*)d_in[5];
  const float* bout   = (const float*)d_in[6];
  const float* h0     = (const float*)d_in[7];
  float* out = (float*)d_out;

  char* ws = (char*)d_ws;
  uint4*    WQ     = (uint4*)ws;                          // 512 KB
  float*    WoT    = (float*)(ws + (512u << 10));         // 512 KB
  uint2*    Wihb32 = (uint2*)(ws + (1024u << 10));        // 256 KB
  float*    BS     = (float*)(ws + (1280u << 10));        // 2 KB
  uint16_t* XP     = (uint16_t*)(ws + (1536u << 10));     // 64 MB

  hipLaunchKernelGGL(prep_kernel, dim3(386), dim3(256), 0, stream,
                     Whh, Wih, Wout, bih, bhh, WQ, WoT, Wihb32, BS);
  hipLaunchKernelGGL(xproj_kernel, dim3(NB * NT / 64), dim3(256), 0, stream,
                     inputs, (const uint16_t*)Wihb32, BS, XP);
  hipLaunchKernelGGL(recur_kernel, dim3(NB), dim3(512), 0, stream,
                     WQ, WoT, XP, h0, bout, out);
}